// Round 5
// baseline (94.961 us; speedup 1.0000x reference)
//
#include <hip/hip_runtime.h>

// NeuralCA: out = clip(x + sum_k sigmoid(10*(conv3x3_k(x) - r_k)) * (p_k - x), 0, 1)
// B=16, H=W=512, NK=16, fp32. VALU-issue-bound (8% HBM, MfmaUtil 0).
// R5 theory: per pair-k cycle budget is dominated by trans ops if v_exp/v_rcp run
// at ~16 cyc/wave64 (R4 ~30us kernel vs 12.4us floor @trans=8 fits trans=16 model).
// Changes vs R4: (a) exp-only sigmoid (reflection + packed deg-5 poly of 1/(1+e)-0.5,
// numerics proven in R3: absmax 0.0039): 4 trans -> 2 trans per pair-k;
// (b) GAIN folded into weights/reactant on the scalar pipe: conv produces t
// directly, deleting the z-FMA; (c) -|t| folds into v_exp_f32 src modifiers.

#define NK 16
#define BATCH 16
#define H 512
#define W 512
#define G2 14.4269504088896340f   // GAIN(=10) * log2(e)

typedef float f2 __attribute__((ext_vector_type(2)));

#if __has_builtin(__builtin_amdgcn_exp2f)
#define EXP2F(x) __builtin_amdgcn_exp2f(x)
#else
#define EXP2F(x) exp2f(x)
#endif

#if __has_builtin(__builtin_elementwise_fma)
#define FMA2(a, b, c) __builtin_elementwise_fma((a), (b), (c))
#else
#define FMA2(a, b, c) ((a) * (b) + (c))   // fp-contract folds to fma.v2f32
#endif

// q(e) = 1/(1+e) - 0.5 on [0,1]; deg-5 Chebyshev truncation, |err| < 5e-5 (R3-proven).
#define P0 0.49995667f
#define P1 -0.99662610f
#define P2 0.95608720f
#define P3 -0.77780000f
#define P4 0.42600960f
#define P5 -0.10765824f

static __device__ __forceinline__ f2 bc2(float s) { f2 r; r.x = s; r.y = s; return r; }

// Constant address space -> guaranteed s_load (SGPR broadcast)
typedef const __attribute__((address_space(4))) float cfloat;

__global__ __launch_bounds__(256, 4) void nca_kernel(
    const float* __restrict__ x,
    const float* __restrict__ kernels,
    const float* __restrict__ reactants,
    const float* __restrict__ products,
    float* __restrict__ out)
{
    // One thread per 2x4 pixel tile. Tiles: 16 * 256 * 128 = 2^19 threads.
    const int idx = blockIdx.x * blockDim.x + threadIdx.x;
    const int w4 = (idx & 127) << 2;        // tile start col (128 tiles/row)
    const int h0 = ((idx >> 7) & 255) << 1; // tile start row
    const int b  = idx >> 15;

    const float* xb = x + (size_t)b * (H * W);

    // 4 rows x 6 cols register window (rows h0-1 .. h0+2, halo 1 each side in w)
    float v[4][6];
#pragma unroll
    for (int r = 0; r < 4; ++r) {
        const int row = h0 + r - 1;
        if (row >= 0 && row < H) {
            const float* xr = xb + row * W;
            const float4 c = *(const float4*)(xr + w4);
            v[r][1] = c.x; v[r][2] = c.y; v[r][3] = c.z; v[r][4] = c.w;
            v[r][0] = (w4 > 0)     ? xr[w4 - 1] : 0.0f;   // zero pad left
            v[r][5] = (w4 + 4 < W) ? xr[w4 + 4] : 0.0f;   // zero pad right
        } else {
#pragma unroll
            for (int c = 0; c < 6; ++c) v[r][c] = 0.0f;   // zero pad top/bottom
        }
    }

    // Shifted float2 slices: sl[r][s] = {v[r][s], v[r][s+1]}, s = 0..4.
    // Output pair g (local cols 2g,2g+1), tap c uses sl[r][2g+c]; center = sl[py+1][2g+1].
    f2 sl[4][5];
#pragma unroll
    for (int r = 0; r < 4; ++r)
#pragma unroll
        for (int s = 0; s < 5; ++s) { sl[r][s].x = v[r][s]; sl[r][s].y = v[r][s + 1]; }

    cfloat* kc = (cfloat*)kernels;
    cfloat* rc = (cfloat*)reactants;
    cfloat* pc = (cfloat*)products;

    // sum_k p_k (scalar pipe, uniform)
    float sumP = 0.0f;
#pragma unroll
    for (int k = 0; k < NK; ++k) sumP += pc[k];

    // sig_k = 0.5 + sq_k, sq_k = copysign(1/(1+2^-|t|) - 0.5, t), t = G2*(N - r_k)
    // sum_k sig_k       = 8 + sum_k sq_k
    // sum_k sig_k * p_k = 0.5*sumP + sum_k sq_k * p_k
    f2 s0[2][2], s1[2][2];
#pragma unroll
    for (int py = 0; py < 2; ++py)
#pragma unroll
        for (int g = 0; g < 2; ++g) { s0[py][g] = bc2(0.0f); s1[py][g] = bc2(0.0f); }

#pragma unroll
    for (int k = 0; k < NK; ++k) {
        // GAIN pre-folded on the scalar pipe: conv with gw accumulates t directly.
        f2 gw[9];
#pragma unroll
        for (int i = 0; i < 9; ++i) gw[i] = bc2(G2 * kc[k * 9 + i]);
        const f2 c2 = bc2(-G2 * rc[k]);   // accumulator seed: t = sum gw*v + c2
        const float pk = pc[k];

#pragma unroll
        for (int py = 0; py < 2; ++py) {
#pragma unroll
            for (int g = 0; g < 2; ++g) {
                f2 t = c2;
#pragma unroll
                for (int r = 0; r < 3; ++r)
#pragma unroll
                    for (int c = 0; c < 3; ++c)
                        t = FMA2(sl[py + r][2 * g + c], gw[r * 3 + c], t);
                f2 e;
                e.x = EXP2F(-__builtin_fabsf(t.x));   // src mods fold: v_exp_f32 -|t|
                e.y = EXP2F(-__builtin_fabsf(t.y));
                f2 q = FMA2(bc2(P5), e, bc2(P4));     // packed poly: q = 1/(1+e) - 0.5
                q = FMA2(q, e, bc2(P3));
                q = FMA2(q, e, bc2(P2));
                q = FMA2(q, e, bc2(P1));
                q = FMA2(q, e, bc2(P0));
                f2 sq;
                sq.x = copysignf(q.x, t.x);           // v_bfi_b32
                sq.y = copysignf(q.y, t.y);
                s0[py][g] = s0[py][g] + sq;           // pk add
                s1[py][g] = FMA2(sq, bc2(pk), s1[py][g]); // pk fma
            }
        }
    }

#pragma unroll
    for (int py = 0; py < 2; ++py) {
        float4 o;
#pragma unroll
        for (int g = 0; g < 2; ++g) {
            const f2 xv = sl[py + 1][2 * g + 1];      // center pixels of pair
            const f2 sigsum = bc2(8.0f) + s0[py][g];
            f2 sigp = s1[py][g];
            sigp.x = fmaf(0.5f, sumP, sigp.x);
            sigp.y = fmaf(0.5f, sumP, sigp.y);
            f2 res = FMA2(-xv, sigsum, xv + sigp);
            res.x = fminf(fmaxf(res.x, 0.0f), 1.0f);
            res.y = fminf(fmaxf(res.y, 0.0f), 1.0f);
            if (g == 0) { o.x = res.x; o.y = res.y; }
            else        { o.z = res.x; o.w = res.y; }
        }
        *(float4*)(out + ((size_t)(b * H + h0 + py) * W + w4)) = o;
    }
}

extern "C" void kernel_launch(void* const* d_in, const int* in_sizes, int n_in,
                              void* d_out, int out_size, void* d_ws, size_t ws_size,
                              hipStream_t stream) {
    const float* x         = (const float*)d_in[0];
    const float* kernels   = (const float*)d_in[1];
    const float* reactants = (const float*)d_in[2];
    const float* products  = (const float*)d_in[3];
    float* out = (float*)d_out;

    const int total_tiles = BATCH * (H / 2) * (W / 4);  // 2^19
    nca_kernel<<<total_tiles / 256, 256, 0, stream>>>(x, kernels, reactants, products, out);
}